// Round 1
// baseline (49.693 us; speedup 1.0000x reference)
//
#include <hip/hip_runtime.h>

#define RL_NB 2048
#define RL_NT 256

__global__ __launch_bounds__(RL_NT) void rl_partial_kernel(
    const float4* __restrict__ p4, const float4* __restrict__ t4,
    float* __restrict__ ws, int n4) {
  float acc = 0.0f;
  int idx = blockIdx.x * blockDim.x + threadIdx.x;
  int stride = gridDim.x * blockDim.x;
  for (int i = idx; i < n4; i += stride) {
    float4 p = p4[i];
    float4 t = t4[i];
    {
      float pp = p.x, tt = t.x;
      bool m = (pp * 1.1f > tt) && (pp * 0.9f < tt);
      float d = pp - tt;
      acc += m ? 0.0f : d * d;
    }
    {
      float pp = p.y, tt = t.y;
      bool m = (pp * 1.1f > tt) && (pp * 0.9f < tt);
      float d = pp - tt;
      acc += m ? 0.0f : d * d;
    }
    {
      float pp = p.z, tt = t.z;
      bool m = (pp * 1.1f > tt) && (pp * 0.9f < tt);
      float d = pp - tt;
      acc += m ? 0.0f : d * d;
    }
    {
      float pp = p.w, tt = t.w;
      bool m = (pp * 1.1f > tt) && (pp * 0.9f < tt);
      float d = pp - tt;
      acc += m ? 0.0f : d * d;
    }
  }
  // wave64 reduce
  #pragma unroll
  for (int off = 32; off > 0; off >>= 1)
    acc += __shfl_down(acc, off, 64);
  __shared__ float smem[RL_NT / 64];
  int lane = threadIdx.x & 63;
  int wid = threadIdx.x >> 6;
  if (lane == 0) smem[wid] = acc;
  __syncthreads();
  if (threadIdx.x == 0) {
    float b = 0.0f;
    #pragma unroll
    for (int i = 0; i < RL_NT / 64; ++i) b += smem[i];
    ws[blockIdx.x] = b;
  }
}

__global__ __launch_bounds__(RL_NT) void rl_final_kernel(
    const float* __restrict__ ws, float* __restrict__ out, double inv_n) {
  double acc = 0.0;
  for (int i = threadIdx.x; i < RL_NB; i += blockDim.x)
    acc += (double)ws[i];
  #pragma unroll
  for (int off = 32; off > 0; off >>= 1)
    acc += __shfl_down(acc, off, 64);
  __shared__ double smem[RL_NT / 64];
  int lane = threadIdx.x & 63;
  int wid = threadIdx.x >> 6;
  if (lane == 0) smem[wid] = acc;
  __syncthreads();
  if (threadIdx.x == 0) {
    double b = 0.0;
    #pragma unroll
    for (int i = 0; i < RL_NT / 64; ++i) b += smem[i];
    out[0] = (float)(b * inv_n);
  }
}

extern "C" void kernel_launch(void* const* d_in, const int* in_sizes, int n_in,
                              void* d_out, int out_size, void* d_ws, size_t ws_size,
                              hipStream_t stream) {
  const float* preds  = (const float*)d_in[0];
  const float* target = (const float*)d_in[1];
  float* out = (float*)d_out;
  float* ws = (float*)d_ws;

  long long n = (long long)in_sizes[0];  // 33554432 (N*D, D==1)
  int n4 = (int)(n / 4);                 // divisible by 4

  rl_partial_kernel<<<RL_NB, RL_NT, 0, stream>>>(
      (const float4*)preds, (const float4*)target, ws, n4);
  rl_final_kernel<<<1, RL_NT, 0, stream>>>(ws, out, 1.0 / (double)n);
}

// Round 2
// 46.878 us; speedup vs baseline: 1.0600x; 1.0600x over previous
//
#include <hip/hip_runtime.h>

#define RL_NB 2048
#define RL_NT 256

__device__ __forceinline__ float rl_term(float pp, float tt) {
  bool m = (pp * 1.1f > tt) && (pp * 0.9f < tt);
  float d = pp - tt;
  return m ? 0.0f : d * d;
}

__device__ __forceinline__ float rl_term4(float4 p, float4 t) {
  return rl_term(p.x, t.x) + rl_term(p.y, t.y) +
         rl_term(p.z, t.z) + rl_term(p.w, t.w);
}

__global__ __launch_bounds__(RL_NT) void rl_partial_kernel(
    const float4* __restrict__ p4, const float4* __restrict__ t4,
    float* __restrict__ ws, int n4) {
  float acc = 0.0f;
  int idx = blockIdx.x * blockDim.x + threadIdx.x;
  int stride = gridDim.x * blockDim.x;

  int i = idx;
  // Unrolled-by-4: 8 independent dwordx4 loads in flight per iteration.
  for (; i + 3 * stride < n4; i += 4 * stride) {
    float4 p0 = p4[i];
    float4 p1 = p4[i + stride];
    float4 p2 = p4[i + 2 * stride];
    float4 p3 = p4[i + 3 * stride];
    float4 t0 = t4[i];
    float4 t1 = t4[i + stride];
    float4 t2 = t4[i + 2 * stride];
    float4 t3 = t4[i + 3 * stride];
    acc += rl_term4(p0, t0);
    acc += rl_term4(p1, t1);
    acc += rl_term4(p2, t2);
    acc += rl_term4(p3, t3);
  }
  for (; i < n4; i += stride) {
    acc += rl_term4(p4[i], t4[i]);
  }

  // wave64 reduce
  #pragma unroll
  for (int off = 32; off > 0; off >>= 1)
    acc += __shfl_down(acc, off, 64);
  __shared__ float smem[RL_NT / 64];
  int lane = threadIdx.x & 63;
  int wid = threadIdx.x >> 6;
  if (lane == 0) smem[wid] = acc;
  __syncthreads();
  if (threadIdx.x == 0) {
    float b = 0.0f;
    #pragma unroll
    for (int i2 = 0; i2 < RL_NT / 64; ++i2) b += smem[i2];
    ws[blockIdx.x] = b;
  }
}

__global__ __launch_bounds__(RL_NT) void rl_final_kernel(
    const float* __restrict__ ws, float* __restrict__ out, double inv_n) {
  double acc = 0.0;
  for (int i = threadIdx.x; i < RL_NB; i += blockDim.x)
    acc += (double)ws[i];
  #pragma unroll
  for (int off = 32; off > 0; off >>= 1)
    acc += __shfl_down(acc, off, 64);
  __shared__ double smem[RL_NT / 64];
  int lane = threadIdx.x & 63;
  int wid = threadIdx.x >> 6;
  if (lane == 0) smem[wid] = acc;
  __syncthreads();
  if (threadIdx.x == 0) {
    double b = 0.0;
    #pragma unroll
    for (int i = 0; i < RL_NT / 64; ++i) b += smem[i];
    out[0] = (float)(b * inv_n);
  }
}

extern "C" void kernel_launch(void* const* d_in, const int* in_sizes, int n_in,
                              void* d_out, int out_size, void* d_ws, size_t ws_size,
                              hipStream_t stream) {
  const float* preds  = (const float*)d_in[0];
  const float* target = (const float*)d_in[1];
  float* out = (float*)d_out;
  float* ws = (float*)d_ws;

  long long n = (long long)in_sizes[0];  // 33554432 (N*D, D==1)
  int n4 = (int)(n / 4);                 // divisible by 4

  rl_partial_kernel<<<RL_NB, RL_NT, 0, stream>>>(
      (const float4*)preds, (const float4*)target, ws, n4);
  rl_final_kernel<<<1, RL_NT, 0, stream>>>(ws, out, 1.0 / (double)n);
}